// Round 2
// 1587.388 us; speedup vs baseline: 1.3511x; 1.3511x over previous
//
#include <hip/hip_runtime.h>
#include <stdint.h>

typedef unsigned short ushort_t;
typedef float f32x4 __attribute__((ext_vector_type(4)));
typedef short short8 __attribute__((ext_vector_type(8)));

#define B_ 32
#define T_ 512
#define I_ 512
#define H_ 512
#define G_ 2048   // 4*H

// ---------- helpers ----------
__device__ __forceinline__ ushort_t f2bf(float f) {
    uint32_t u = __float_as_uint(f);
    u += 0x7FFFu + ((u >> 16) & 1u);   // RNE
    return (ushort_t)(u >> 16);
}
__device__ __forceinline__ float bf2f(ushort_t s) {
    return __uint_as_float(((uint32_t)s) << 16);
}
__device__ __forceinline__ float sigm(float x) { return 1.0f / (1.0f + __expf(-x)); }
__device__ __forceinline__ float tanhx(float x) {
    float e = __expf(-2.0f * fabsf(x));
    float t = (1.0f - e) / (1.0f + e);
    return x >= 0.0f ? t : -t;
}

// ---------- cast fp32 -> bf16 (vectorized) ----------
__global__ __launch_bounds__(256) void kcast(const float* __restrict__ in,
                                             ushort_t* __restrict__ out, int n4) {
    int i = blockIdx.x * 256 + threadIdx.x;
    if (i < n4) {
        float4 v = ((const float4*)in)[i];
        ushort4 o;
        o.x = f2bf(v.x); o.y = f2bf(v.y); o.z = f2bf(v.z); o.w = f2bf(v.w);
        ((ushort4*)out)[i] = o;
    }
}

// ---------- bias fold: bias = bx + bh ----------
__global__ __launch_bounds__(256) void kbias(const float* __restrict__ bx,
                                             const float* __restrict__ bh,
                                             float* __restrict__ bias) {
    int i = blockIdx.x * 256 + threadIdx.x;
    if (i < G_) bias[i] = bx[i] + bh[i];
}

// ---------- GEMM: gx[m][n'] = sum_k xb[m][k]*wxb[n][k] + bias[n], bf16 out ----------
// Column layout swizzled for krec: logical n = gate*512 + jj*16 + d  ->  n' = jj*64 + gate*16 + d
// so each recurrence block's per-(b,t) slice is 64 contiguous values.
__global__ __launch_bounds__(256, 2) void kgemm(const ushort_t* __restrict__ A,
                                                const ushort_t* __restrict__ Bm,
                                                const float* __restrict__ bias,
                                                ushort_t* __restrict__ C) {
    __shared__ __align__(16) ushort_t LA[4096];   // [128 rows][32 k] swizzled
    __shared__ __align__(16) ushort_t LB[4096];
    const int tid = threadIdx.x;
    const int lane = tid & 63, w = tid >> 6;
    const int quad = lane >> 4, l16 = lane & 15;
    const int bn = blockIdx.x, bm = blockIdx.y;
    const int wr = w >> 1, wc = w & 1;

    f32x4 acc[4][4] = {};

    for (int kt = 0; kt < 16; ++kt) {
#pragma unroll
        for (int r = 0; r < 2; ++r) {
            int o = r * 256 + tid;           // 16B unit index
            int m = o >> 2, slot = o & 3;
            int kc = slot ^ ((m >> 1) & 3);  // stored slot = kc ^ s(m)
            const ushort_t* ga = A  + (size_t)(bm * 128 + m) * I_ + kt * 32 + kc * 8;
            const ushort_t* gb = Bm + (size_t)(bn * 128 + m) * I_ + kt * 32 + kc * 8;
            __builtin_amdgcn_global_load_lds(
                (const __attribute__((address_space(1))) void*)ga,
                (__attribute__((address_space(3))) void*)(&LA[r * 2048 + w * 512]), 16, 0, 0);
            __builtin_amdgcn_global_load_lds(
                (const __attribute__((address_space(1))) void*)gb,
                (__attribute__((address_space(3))) void*)(&LB[r * 2048 + w * 512]), 16, 0, 0);
        }
        __syncthreads();

        short8 av[4], bv[4];
#pragma unroll
        for (int mt = 0; mt < 4; ++mt) {
            int mm = wr * 64 + mt * 16 + l16;
            av[mt] = *(const short8*)&LA[mm * 32 + ((quad ^ ((mm >> 1) & 3)) << 3)];
            int nn = wc * 64 + mt * 16 + l16;
            bv[mt] = *(const short8*)&LB[nn * 32 + ((quad ^ ((nn >> 1) & 3)) << 3)];
        }
#pragma unroll
        for (int mt = 0; mt < 4; ++mt)
#pragma unroll
            for (int nt = 0; nt < 4; ++nt)
                acc[mt][nt] = __builtin_amdgcn_mfma_f32_16x16x32_bf16(av[mt], bv[nt], acc[mt][nt], 0, 0, 0);
        __syncthreads();
    }

#pragma unroll
    for (int nt = 0; nt < 4; ++nt) {
        int n = bn * 128 + wc * 64 + nt * 16 + l16;      // logical gate-space column
        int gate = n >> 9, jj = (n >> 4) & 31, d = n & 15;
        int np = jj * 64 + gate * 16 + d;                // swizzled storage column
        float bvl = bias[n];
#pragma unroll
        for (int mt = 0; mt < 4; ++mt) {
#pragma unroll
            for (int rg = 0; rg < 4; ++rg) {
                int m = bm * 128 + wr * 64 + mt * 16 + quad * 4 + rg;
                C[(size_t)m * G_ + np] = f2bf(acc[mt][nt][rg] + bvl);
            }
        }
    }
}

// ---------- recurrence ----------
// 128 blocks = 4 groups x 32 blocks. Group g: batches g*8..g*8+7, chains 0-7 fwd, 8-15 bwd.
// Block j owns h-dims [j*16, j*16+16); wave w = gate section (i,f,g,o), Wh section in VGPRs.
//
// Cross-block exchange: TAG-IN-DATA. Each 8B unit = {tag:32 | h_odd:bf16 | h_even:bf16},
// tag = step index of the h-state it carries (initial zeros carry tag 0 for step 0).
// Consumers poll the data units directly with agent-scope relaxed 8B atomic loads:
// ONE MALL roundtrip per step instead of three
// (old: store -> waitcnt ack -> flag store -> flag poll -> data load).
//
// Poll predicate is (tag >= n), NOT (tag == n):
//  - In a live run they are equivalent: a producer can only publish tag n+2 after every
//    thread of every block exited poll(n) (block's first __syncthreads orders polls before
//    stores; step-(n+1) poll transitively requires all step-n stores). So inside poll(n)
//    only tags n-2 / n are observable.
//  - Under harness re-execution against unrestored state (rocprof kernel replay), tags are
//    left at 511/512 from the previous run; '==' spins forever -> GPU hang -> dead container
//    (round-1 failure mode). '>=' terminates instantly, like round-0's flag poll did.
//  - Belt-and-braces: spin cap (~1s) converts any residual protocol bug into a wrong-answer
//    bench (with counters) instead of a hung container.
//
// Unit index within a group parity buffer: u = chain*256 + jblk*8 + pair  (pair = dim/2 within
// jblk's 16 dims). 16 chains * 256 units * 8B = 32KB per parity.
__global__ __launch_bounds__(256, 2) void krec(const ushort_t* __restrict__ gx,
                                               const ushort_t* __restrict__ whb,
                                               unsigned long long* __restrict__ hg,
                                               float* __restrict__ out) {
    __shared__ __align__(16) ushort_t hl[16 * 520];   // h tile, padded stride
    __shared__ float gates[4][16][16];                // [gate][chain][dim]
    const int tid = threadIdx.x;
    const int lane = tid & 63, w = tid >> 6;
    const int quad = lane >> 4, l16 = lane & 15;
    const int bk = blockIdx.x, grp = bk >> 5, j = bk & 31;

    // Wh B-frags for this wave's gate section, cols j*16..+16 (rows of Wh = gate outputs)
    short8 bw[16];
    {
        const ushort_t* wp = whb + (size_t)(w * H_ + j * 16 + l16) * H_ + quad * 8;
#pragma unroll
        for (int kc = 0; kc < 16; ++kc) bw[kc] = *(const short8*)(wp + kc * 32);
    }

    const int r = tid >> 4, d = tid & 15;     // chain, dim for cell update / consumer role
    const int b = grp * 8 + (r & 7), dir = r >> 3;
    float c = 0.0f;                           // cell state in register

    unsigned long long* hgrp = hg + (size_t)grp * 8192;   // 2 parities x 4096 units

    // Consumer thread t polls units covering chain r, dims [cc*128 + 8d, +8) for cc=0..3:
    // unit idx = r*256 + cc*64 + d*4 + k  (k=0..3, each unit = 2 dims).
    const int base0 = r * 256 + d * 4;

    for (int n = 0; n < 512; ++n) {
        // ---- prefetch gx for this step (independent of h, overlaps the poll) ----
        int te = dir ? (511 - n) : n;
        const ushort_t* gp = gx + (size_t)(b * T_ + te) * G_ + j * 64 + d;
        ushort_t g0 = gp[0], g1 = gp[16], g2 = gp[32], g3 = gp[48];

        // ---- poll tagged h units (tag >= n, see header), parity n&1 ----
        const unsigned long long* hsrc = hgrp + (size_t)(n & 1) * 4096 + base0;
        unsigned long long tv[16];
        for (int spin = 0; spin < (1 << 22); ++spin) {
#pragma unroll
            for (int i = 0; i < 16; ++i)
                tv[i] = __hip_atomic_load(hsrc + (i >> 2) * 64 + (i & 3),
                                          __ATOMIC_RELAXED, __HIP_MEMORY_SCOPE_AGENT);
            bool ok = true;
#pragma unroll
            for (int i = 0; i < 16; ++i)
                ok &= ((uint32_t)(tv[i] >> 32) >= (uint32_t)n);
            if (ok) break;
        }

        // ---- unpack to LDS: 4x ds_write_b128, conflict-free (8 lanes cover 32 banks) ----
#pragma unroll
        for (int cc = 0; cc < 4; ++cc) {
            uint4 pk;
            pk.x = (uint32_t)tv[cc * 4 + 0];
            pk.y = (uint32_t)tv[cc * 4 + 1];
            pk.z = (uint32_t)tv[cc * 4 + 2];
            pk.w = (uint32_t)tv[cc * 4 + 3];
            *(uint4*)&hl[r * 520 + d * 8 + cc * 128] = pk;
        }
        __syncthreads();

        // ---- gates = h @ Wh_section^T (two independent MFMA chains) ----
        f32x4 acc0 = {}, acc1 = {};
#pragma unroll
        for (int kc = 0; kc < 16; kc += 2) {
            short8 av0 = *(const short8*)&hl[l16 * 520 + kc * 32 + quad * 8];
            acc0 = __builtin_amdgcn_mfma_f32_16x16x32_bf16(av0, bw[kc], acc0, 0, 0, 0);
            short8 av1 = *(const short8*)&hl[l16 * 520 + (kc + 1) * 32 + quad * 8];
            acc1 = __builtin_amdgcn_mfma_f32_16x16x32_bf16(av1, bw[kc + 1], acc1, 0, 0, 0);
        }
        f32x4 acc = acc0 + acc1;
#pragma unroll
        for (int rg = 0; rg < 4; ++rg) gates[w][quad * 4 + rg][l16] = acc[rg];
        __syncthreads();

        // ---- cell update: thread -> (chain r, dim d) ----
        float gi = gates[0][r][d] + bf2f(g0);
        float gf = gates[1][r][d] + bf2f(g1);
        float gg = gates[2][r][d] + bf2f(g2);
        float go = gates[3][r][d] + bf2f(g3);
        float it = sigm(gi), ft = sigm(gf), gt = tanhx(gg), ot = sigm(go);
        c = c * ft + it * gt;
        float h = ot * tanhx(c);

        // ---- pack pair + tag, fire-and-forget store to parity (n+1)&1 ----
        // No waitcnt, no flag: consumers detect via the tag inside the unit.
        int hv = (int)f2bf(h);
        int vo = __shfl(hv, lane ^ 1);
        if (!(d & 1)) {
            unsigned long long unit = ((unsigned long long)(uint32_t)(n + 1) << 32)
                                    | (((uint32_t)vo & 0xFFFFu) << 16)
                                    | ((uint32_t)hv & 0xFFFFu);
            __hip_atomic_store(hgrp + (size_t)((n + 1) & 1) * 4096 + (size_t)r * 256 + j * 8 + (d >> 1),
                               unit, __ATOMIC_RELAXED, __HIP_MEMORY_SCOPE_AGENT);
        }
        out[(size_t)b * (T_ * 2 * H_) + (size_t)n * (2 * H_) + dir * H_ + j * 16 + d] = h;
    }
}

// ---------- workspace layout (bytes) ----------
// HG aliases XB: xb is dead after kgemm, and the HG memset is issued after kgemm in-stream.
#define GX_OFF    ((size_t)0)                    // 16384*2048*2 = 67108864
#define XB_OFF    ((size_t)67108864)             // 16384*512*2 = 16777216
#define HG_OFF    XB_OFF                         // 4 grp * 2 par * 4096 units * 8B = 262144
#define HG_BYTES  ((size_t)262144)
#define WXB_OFF   ((size_t)83886080)             // 2048*512*2  = 2097152
#define WHB_OFF   ((size_t)85983232)             // 2048*512*2  = 2097152
#define BIAS_OFF  ((size_t)88080384)             // 2048*4      = 8192
#define WS_NEED   ((size_t)88088576)

extern "C" void kernel_launch(void* const* d_in, const int* in_sizes, int n_in,
                              void* d_out, int out_size, void* d_ws, size_t ws_size,
                              hipStream_t stream) {
    if (ws_size < WS_NEED) return;

    const float* x  = (const float*)d_in[0];
    const float* Wx = (const float*)d_in[1];
    const float* bx = (const float*)d_in[2];
    const float* Wh = (const float*)d_in[3];
    const float* bh = (const float*)d_in[4];
    float* out = (float*)d_out;
    char* ws = (char*)d_ws;

    ushort_t* gx   = (ushort_t*)(ws + GX_OFF);
    ushort_t* xb   = (ushort_t*)(ws + XB_OFF);
    ushort_t* wxb  = (ushort_t*)(ws + WXB_OFF);
    ushort_t* whb  = (ushort_t*)(ws + WHB_OFF);
    float*    bias = (float*)(ws + BIAS_OFF);
    unsigned long long* hg = (unsigned long long*)(ws + HG_OFF);

    // casts
    kcast<<<dim3((B_ * T_ * I_ / 4 + 255) / 256), 256, 0, stream>>>(x, xb, B_ * T_ * I_ / 4);
    kcast<<<dim3((G_ * I_ / 4 + 255) / 256), 256, 0, stream>>>(Wx, wxb, G_ * I_ / 4);
    kcast<<<dim3((G_ * H_ / 4 + 255) / 256), 256, 0, stream>>>(Wh, whb, G_ * H_ / 4);
    kbias<<<dim3(G_ / 256), 256, 0, stream>>>(bx, bh, bias);

    // input projection GEMM: grid (N/128, M/128) = (16, 128)
    kgemm<<<dim3(G_ / 128, (B_ * T_) / 128), 256, 0, stream>>>(xb, wxb, bias, gx);

    // zero tagged h double-buffer (tag 0 == valid initial state for step 0).
    // Must run after kgemm: HG aliases the then-dead xb region.
    hipMemsetAsync(ws + HG_OFF, 0, HG_BYTES, stream);

    // recurrence: 128 persistent blocks (4 groups x 32)
    krec<<<dim3(128), 256, 0, stream>>>(gx, whb, hg, out);
}